// Round 6
// baseline (269.852 us; speedup 1.0000x reference)
//
#include <hip/hip_runtime.h>

#define N_INPUTS 16384
#define N_DET    65536
#define KD       32
#define BATCH    32
#define SLICES   32                        // det slices (2048 det each)
#define QUADS    8                         // 4 batch rows per block
#define DPB      (N_DET / SLICES)          // 2048 detectors per block
#define THREADS  512                       // 8 waves, 1 block/CU (139 KB LDS)

typedef unsigned short u16x4 __attribute__((ext_vector_type(4)));

// monotone 16-bit sort key for f32: a<=b  <=>  key16(a)<=key16(b)
__device__ __forceinline__ unsigned short key16(float f) {
    unsigned b = __float_as_uint(f);
    unsigned m = ((unsigned)((int)b >> 31)) | 0x80000000u;
    return (unsigned short)((b ^ m) >> 16);
}

// compact bits {q, q+4, ..., q+28} of v into a byte
__device__ __forceinline__ unsigned c8(unsigned v, int q) {
    v = (v >> q) & 0x11111111u;
    v = (v | (v >> 3)) & 0x03030303u;
    v = (v | (v >> 6)) & 0x000F000Fu;
    v = (v | (v >> 12)) & 0xFFu;
    return v;
}

// ---------------------------------------------------------------------------
// prep: xq[quad][i] = packed key16 of x[4q..4q+3][i]. 4 coalesced streams.
// ---------------------------------------------------------------------------
__global__ __launch_bounds__(1024) void prep(const float* __restrict__ x,
                                             unsigned long long* __restrict__ xq) {
    const int gid  = blockIdx.x * 1024 + threadIdx.x;    // 0 .. 8*16384-1
    const int quad = gid >> 14, i = gid & (N_INPUTS - 1);
    const float* xb = x + (size_t)quad * 4 * N_INPUTS + i;
    unsigned long long k = 0;
#pragma unroll
    for (int q = 0; q < 4; ++q)
        k |= (unsigned long long)key16(xb[(size_t)q * N_INPUTS]) << (16 * q);
    xq[gid] = k;
}

// ---------------------------------------------------------------------------
// inhibit: one block = (4 batch rows as packed key16 quads) x (2048-det
// slice). Per detector: 32 ds_read_b64 gathers serve FOUR batches (half the
// DS instructions and half the DS words per batch-element of every prior
// round). Max via 31 packed u16 elementwise-max (v_pk_max_u16). Per batch:
// candidate mask eq = slots attaining the key-max. Singleton eq (~98%) is the
// exact argmax; multi-candidate dets push an (d,b,eq) record for exact repair
// from global f32. Lose nibbles (4 bits/input) exclude ALL candidates, so
// inhibit itself never resolves ties. Pack phase emits u32 pm words.
// ---------------------------------------------------------------------------
__global__ __launch_bounds__(THREADS, 2) void inhibit(
        const unsigned long long* __restrict__ xq,
        const int* __restrict__ det,
        unsigned* __restrict__ pm,
        unsigned* __restrict__ qcnt,
        unsigned* __restrict__ queue) {
    __shared__ __align__(16) unsigned long long xs[N_INPUTS]; // 128 KB keys
    __shared__ unsigned fl[N_INPUTS / 8];                     // 8 KB nibbles

    const int slice = blockIdx.x;
    const int quad  = blockIdx.y;
    const int tid   = threadIdx.x;

#pragma unroll
    for (int k = 0; k < (N_INPUTS / 8) / THREADS; ++k)
        fl[tid + k * THREADS] = 0u;

    // stage the quad's packed keys: 16 KB per wave, coalesced 16B loads
    const ulonglong2* src = (const ulonglong2*)(xq + (size_t)quad * N_INPUTS);
    ulonglong2* dst = (ulonglong2*)xs;
#pragma unroll
    for (int k = 0; k < N_INPUTS / 2 / THREADS; ++k)
        dst[tid + k * THREADS] = src[tid + k * THREADS];
    __syncthreads();

    const int4* det4 = (const int4*)det;
    const u16x4* xsv = (const u16x4*)xs;

#pragma unroll 1
    for (int j = 0; j < DPB / THREADS; ++j) {      // 4 detectors per thread
        const int   d    = slice * DPB + j * THREADS + tid;
        const int4* drow = det4 + (size_t)d * 8;
        int ids[KD];
#pragma unroll
        for (int q = 0; q < 8; ++q) {
            int4 r = drow[q];
            ids[q * 4 + 0] = r.x; ids[q * 4 + 1] = r.y;
            ids[q * 4 + 2] = r.z; ids[q * 4 + 3] = r.w;
        }

        u16x4 k[KD];                               // 32-deep b64 burst, 4 rows
#pragma unroll
        for (int s = 0; s < KD; ++s) k[s] = xsv[ids[s]];

        // packed-u16 max tree (log depth, static indices)
        u16x4 t[16];
#pragma unroll
        for (int i = 0; i < 16; ++i) t[i] = __builtin_elementwise_max(k[2 * i], k[2 * i + 1]);
#pragma unroll
        for (int i = 0; i < 8; ++i)  t[i] = __builtin_elementwise_max(t[2 * i], t[2 * i + 1]);
#pragma unroll
        for (int i = 0; i < 4; ++i)  t[i] = __builtin_elementwise_max(t[2 * i], t[2 * i + 1]);
        t[0] = __builtin_elementwise_max(t[0], t[1]);
        t[2] = __builtin_elementwise_max(t[2], t[3]);
        const u16x4 km = __builtin_elementwise_max(t[0], t[2]);

        // candidate masks per batch (slots attaining the key-max)
        unsigned eq0 = 0, eq1 = 0, eq2 = 0, eq3 = 0;
#pragma unroll
        for (int s = 0; s < KD; ++s) {
            eq0 |= (unsigned)(k[s][0] == km[0]) << s;
            eq1 |= (unsigned)(k[s][1] == km[1]) << s;
            eq2 |= (unsigned)(k[s][2] == km[2]) << s;
            eq3 |= (unsigned)(k[s][3] == km[3]) << s;
        }

        // lose nibble: bit q clear iff slot is a batch-q candidate
#pragma unroll
        for (int s = 0; s < KD; ++s) {
            unsigned nib = 0xFu ^ (((eq0 >> s) & 1u) | (((eq1 >> s) & 1u) << 1) |
                                  (((eq2 >> s) & 1u) << 2) | (((eq3 >> s) & 1u) << 3));
            int id = ids[s];
            atomicOr(&fl[id >> 3], nib << ((id & 7) * 4));
        }

        // multi-candidate batches -> defer exact resolution to repair kernel
#pragma unroll
        for (int q = 0; q < 4; ++q) {
            unsigned eqq = (q == 0) ? eq0 : (q == 1) ? eq1 : (q == 2) ? eq2 : eq3;
            if (__builtin_popcount(eqq) > 1) {
                unsigned pos = atomicAdd(qcnt, 1u);
                queue[2 * pos]     = (unsigned)d | ((unsigned)(quad * 4 + q) << 16);
                queue[2 * pos + 1] = eqq;
            }
        }
    }
    __syncthreads();

    // pack: pm word t covers inputs [32t, 32t+32) for each of the 4 batches
#pragma unroll 1
    for (int q = 0; q < 4; ++q) {
        unsigned w0 = fl[4 * tid + 0], w1 = fl[4 * tid + 1];
        unsigned w2 = fl[4 * tid + 2], w3 = fl[4 * tid + 3];
        unsigned out32 = c8(w0, q) | (c8(w1, q) << 8) | (c8(w2, q) << 16) | (c8(w3, q) << 24);
        pm[((size_t)(slice * BATCH + quad * 4 + q)) * (N_INPUTS / 32) + tid] = out32;
    }
}

// ---------------------------------------------------------------------------
// repair: resolve multi-candidate (det, batch) records exactly from global
// f32 x; OR lose bits for the false candidates into pm. ~50K records.
// ---------------------------------------------------------------------------
__global__ __launch_bounds__(256) void repair(const int* __restrict__ det,
                                              const float* __restrict__ x,
                                              const unsigned* __restrict__ queue,
                                              const unsigned* __restrict__ qcnt,
                                              unsigned* __restrict__ pm) {
    const unsigned total = *qcnt;
    for (unsigned idx = blockIdx.x * 256 + threadIdx.x; idx < total;
         idx += gridDim.x * 256) {
        const unsigned rec = queue[2 * idx];
        const unsigned eq  = queue[2 * idx + 1];
        const int d = rec & 0xFFFFu, b = rec >> 16;
        const int* drow = det + (size_t)d * KD;
        const float* xb = x + (size_t)b * N_INPUTS;

        float best = -__builtin_inff(); int bs = 0;
        unsigned m = eq;
        while (m) {                                  // ascending slots
            int s = __builtin_ctz(m); m &= m - 1;
            float v = xb[drow[s]];
            if (v > best) { best = v; bs = s; }      // strict > = first-max
        }
        m = eq & ~(1u << bs);
        const unsigned base = (unsigned)((d >> 11) * BATCH + b) * (N_INPUTS / 32);
        while (m) {
            int s = __builtin_ctz(m); m &= m - 1;
            int id = drow[s];
            atomicOr(&pm[base + (id >> 5)], 1u << (id & 31));
        }
    }
}

// ---------------------------------------------------------------------------
// finalize: thread = (batch, 32-input group). OR the 32 slice words, emit
// 32 floats as 8 float4 stores. Total read traffic 2 MB.
// ---------------------------------------------------------------------------
__global__ __launch_bounds__(256) void finalize(const unsigned* __restrict__ pm,
                                                float* __restrict__ out) {
    const int t = blockIdx.x * 256 + threadIdx.x;   // 0 .. 32*512-1
    const int b = t >> 9, g = t & 511;
    unsigned acc = 0;
#pragma unroll
    for (int s = 0; s < SLICES; ++s)
        acc |= pm[((size_t)(s * BATCH + b)) * (N_INPUTS / 32) + g];
    float4* o = (float4*)(out + (size_t)b * N_INPUTS + g * 32);
#pragma unroll
    for (int v = 0; v < 8; ++v) {
        float4 r;
        r.x = ((acc >> (4 * v + 0)) & 1u) ? 0.0f : 1.0f;
        r.y = ((acc >> (4 * v + 1)) & 1u) ? 0.0f : 1.0f;
        r.z = ((acc >> (4 * v + 2)) & 1u) ? 0.0f : 1.0f;
        r.w = ((acc >> (4 * v + 3)) & 1u) ? 0.0f : 1.0f;
        o[v] = r;
    }
}

extern "C" void kernel_launch(void* const* d_in, const int* in_sizes, int n_in,
                              void* d_out, int out_size, void* d_ws, size_t ws_size,
                              hipStream_t stream) {
    const float* x   = (const float*)d_in[0];              // [B, N_INPUTS] f32
    const int*   det = (const int*)d_in[1];                // [N_DET, K] i32

    // ws layout: pm 2MB | qcnt (4KB pad) | queue 16MB | xq 1MB
    unsigned* pm   = (unsigned*)d_ws;
    unsigned* qcnt = (unsigned*)((char*)d_ws + (2u << 20));
    unsigned* queue = (unsigned*)((char*)d_ws + (2u << 20) + 4096);
    unsigned long long* xq =
        (unsigned long long*)((char*)d_ws + (18u << 20) + 4096);

    prep<<<QUADS * N_INPUTS / 1024, 1024, 0, stream>>>(x, xq);
    hipMemsetAsync(qcnt, 0, 4, stream);
    dim3 grid(SLICES, QUADS);
    inhibit<<<grid, THREADS, 0, stream>>>(xq, det, pm, qcnt, queue);
    repair<<<64, 256, 0, stream>>>(det, x, queue, qcnt, pm);
    finalize<<<BATCH * (N_INPUTS / 32) / 256, 256, 0, stream>>>(pm, (float*)d_out);
}

// Round 7
// 96.210 us; speedup vs baseline: 2.8048x; 2.8048x over previous
//
#include <hip/hip_runtime.h>

#define N_INPUTS 16384
#define N_DET    65536
#define KD       32
#define BATCH    32
#define SLICES   32                        // det slices (2048 det each)
#define QUADS    8                         // 4 batch rows per block
#define DPB      (N_DET / SLICES)          // 2048 detectors per block
#define THREADS  512                       // 8 waves, 1 block/CU (136 KB LDS)

typedef unsigned short u16x4 __attribute__((ext_vector_type(4)));

// monotone 16-bit sort key for f32: a<=b  <=>  key16(a)<=key16(b)
__device__ __forceinline__ unsigned short key16(float f) {
    unsigned b = __float_as_uint(f);
    unsigned m = ((unsigned)((int)b >> 31)) | 0x80000000u;
    return (unsigned short)((b ^ m) >> 16);
}

// compact bits {q, q+4, ..., q+28} of v into a byte
__device__ __forceinline__ unsigned c8(unsigned v, int q) {
    v = (v >> q) & 0x11111111u;
    v = (v | (v >> 3)) & 0x03030303u;
    v = (v | (v >> 6)) & 0x000F000Fu;
    v = (v | (v >> 12)) & 0xFFu;
    return v;
}

// ---------------------------------------------------------------------------
// prep: xq[quad][i] = packed key16 of x[4q..4q+3][i]. 4 coalesced streams.
// ---------------------------------------------------------------------------
__global__ __launch_bounds__(1024) void prep(const float* __restrict__ x,
                                             unsigned long long* __restrict__ xq) {
    const int gid  = blockIdx.x * 1024 + threadIdx.x;    // 0 .. 8*16384-1
    const int quad = gid >> 14, i = gid & (N_INPUTS - 1);
    const float* xb = x + (size_t)quad * 4 * N_INPUTS + i;
    unsigned long long k = 0;
#pragma unroll
    for (int q = 0; q < 4; ++q)
        k |= (unsigned long long)key16(xb[(size_t)q * N_INPUTS]) << (16 * q);
    xq[gid] = k;
}

// ---------------------------------------------------------------------------
// inhibit: one block = (4 batch rows as packed key16 quads) x (2048-det
// slice). Per detector: 32 ds_read_b64 gathers serve FOUR batches (half the
// DS instructions per batch-element of the R0 structure). Max via packed u16
// elementwise max tree. Candidate mask per batch = slots attaining the key
// max; the true f32 argmax is ALWAYS a candidate (key16 is monotone).
// Singleton mask (~97%) -> exact winner. Multi-candidate (~2.6%) -> divergent
// in-register resolve re-reading exact f32 from global x (L2/L3-resident) --
// NO global queue / NO same-address device atomics (R6's 196us stall was
// ~50K wave-serialized returning atomicAdds on one qcnt address).
// Lose nibbles: bit q clear only at batch-q's exact winner slot.
// ---------------------------------------------------------------------------
__global__ __launch_bounds__(THREADS, 2) void inhibit(
        const unsigned long long* __restrict__ xq,
        const int* __restrict__ det,
        const float* __restrict__ x,
        unsigned* __restrict__ pm) {
    __shared__ __align__(16) unsigned long long xs[N_INPUTS]; // 128 KB keys
    __shared__ unsigned fl[N_INPUTS / 8];                     // 8 KB nibbles

    const int slice = blockIdx.x;
    const int quad  = blockIdx.y;
    const int tid   = threadIdx.x;

#pragma unroll
    for (int k = 0; k < (N_INPUTS / 8) / THREADS; ++k)
        fl[tid + k * THREADS] = 0u;

    // stage the quad's packed keys: coalesced 16B loads
    const ulonglong2* src = (const ulonglong2*)(xq + (size_t)quad * N_INPUTS);
    ulonglong2* dst = (ulonglong2*)xs;
#pragma unroll
    for (int k = 0; k < N_INPUTS / 2 / THREADS; ++k)
        dst[tid + k * THREADS] = src[tid + k * THREADS];
    __syncthreads();

    const int4* det4 = (const int4*)det;
    const u16x4* xsv = (const u16x4*)xs;

#pragma unroll 1
    for (int j = 0; j < DPB / THREADS; ++j) {      // 4 detectors per thread
        const int   d    = slice * DPB + j * THREADS + tid;
        const int4* drow = det4 + (size_t)d * 8;
        int ids[KD];
#pragma unroll
        for (int q = 0; q < 8; ++q) {
            int4 r = drow[q];
            ids[q * 4 + 0] = r.x; ids[q * 4 + 1] = r.y;
            ids[q * 4 + 2] = r.z; ids[q * 4 + 3] = r.w;
        }

        u16x4 k[KD];                               // 32-deep b64 burst, 4 rows
#pragma unroll
        for (int s = 0; s < KD; ++s) k[s] = xsv[ids[s]];

        // packed-u16 max tree (log depth, static indices)
        u16x4 t[16];
#pragma unroll
        for (int i = 0; i < 16; ++i) t[i] = __builtin_elementwise_max(k[2 * i], k[2 * i + 1]);
#pragma unroll
        for (int i = 0; i < 8; ++i)  t[i] = __builtin_elementwise_max(t[2 * i], t[2 * i + 1]);
#pragma unroll
        for (int i = 0; i < 4; ++i)  t[i] = __builtin_elementwise_max(t[2 * i], t[2 * i + 1]);
        t[0] = __builtin_elementwise_max(t[0], t[1]);
        t[2] = __builtin_elementwise_max(t[2], t[3]);
        const u16x4 km = __builtin_elementwise_max(t[0], t[2]);

        // candidate masks per batch (slots attaining the key-max)
        unsigned eq0 = 0, eq1 = 0, eq2 = 0, eq3 = 0;
#pragma unroll
        for (int s = 0; s < KD; ++s) {
            eq0 |= (unsigned)(k[s][0] == km[0]) << s;
            eq1 |= (unsigned)(k[s][1] == km[1]) << s;
            eq2 |= (unsigned)(k[s][2] == km[2]) << s;
            eq3 |= (unsigned)(k[s][3] == km[3]) << s;
        }

        // exact winner slot per batch; rare divergent f32 resolve for ties
        int sw0, sw1, sw2, sw3;
#define RESOLVE(EQ, SW, Q)                                                     \
        SW = __builtin_ctz(EQ);                                                \
        if (EQ & (EQ - 1)) {                                                   \
            const float* xb = x + (size_t)(quad * 4 + (Q)) * N_INPUTS;         \
            float best = xb[ids[SW]];                                          \
            unsigned m = EQ & (EQ - 1);                                        \
            do {                                                               \
                int s = __builtin_ctz(m); m &= m - 1;                          \
                float v = xb[ids[s]];                                          \
                if (v > best) { best = v; SW = s; }   /* strict > = first-max */\
            } while (m);                                                       \
        }
        RESOLVE(eq0, sw0, 0)
        RESOLVE(eq1, sw1, 1)
        RESOLVE(eq2, sw2, 2)
        RESOLVE(eq3, sw3, 3)
#undef RESOLVE

        const unsigned w0 = 1u << sw0, w1 = 1u << sw1;
        const unsigned w2 = 1u << sw2, w3 = 1u << sw3;
#pragma unroll
        for (int s = 0; s < KD; ++s) {
            unsigned nib = 0xFu ^ (((w0 >> s) & 1u) | (((w1 >> s) & 1u) << 1) |
                                  (((w2 >> s) & 1u) << 2) | (((w3 >> s) & 1u) << 3));
            int id = ids[s];
            atomicOr(&fl[id >> 3], nib << ((id & 7) * 4));   // ds_or, no rtn
        }
    }
    __syncthreads();

    // pack: pm word tid covers inputs [32*tid, 32*tid+32) for the 4 batches
#pragma unroll 1
    for (int q = 0; q < 4; ++q) {
        unsigned w0 = fl[4 * tid + 0], w1 = fl[4 * tid + 1];
        unsigned w2 = fl[4 * tid + 2], w3 = fl[4 * tid + 3];
        unsigned out32 = c8(w0, q) | (c8(w1, q) << 8) | (c8(w2, q) << 16) | (c8(w3, q) << 24);
        pm[((size_t)(slice * BATCH + quad * 4 + q)) * (N_INPUTS / 32) + tid] = out32;
    }
}

// ---------------------------------------------------------------------------
// finalize: thread = (batch, 32-input group). OR the 32 slice words, emit
// 32 floats as 8 float4 stores. Total read traffic 2 MB.
// ---------------------------------------------------------------------------
__global__ __launch_bounds__(256) void finalize(const unsigned* __restrict__ pm,
                                                float* __restrict__ out) {
    const int t = blockIdx.x * 256 + threadIdx.x;   // 0 .. 32*512-1
    const int b = t >> 9, g = t & 511;
    unsigned acc = 0;
#pragma unroll
    for (int s = 0; s < SLICES; ++s)
        acc |= pm[((size_t)(s * BATCH + b)) * (N_INPUTS / 32) + g];
    float4* o = (float4*)(out + (size_t)b * N_INPUTS + g * 32);
#pragma unroll
    for (int v = 0; v < 8; ++v) {
        float4 r;
        r.x = ((acc >> (4 * v + 0)) & 1u) ? 0.0f : 1.0f;
        r.y = ((acc >> (4 * v + 1)) & 1u) ? 0.0f : 1.0f;
        r.z = ((acc >> (4 * v + 2)) & 1u) ? 0.0f : 1.0f;
        r.w = ((acc >> (4 * v + 3)) & 1u) ? 0.0f : 1.0f;
        o[v] = r;
    }
}

extern "C" void kernel_launch(void* const* d_in, const int* in_sizes, int n_in,
                              void* d_out, int out_size, void* d_ws, size_t ws_size,
                              hipStream_t stream) {
    const float* x   = (const float*)d_in[0];              // [B, N_INPUTS] f32
    const int*   det = (const int*)d_in[1];                // [N_DET, K] i32

    // ws layout: pm 2MB | xq 1MB
    unsigned* pm = (unsigned*)d_ws;
    unsigned long long* xq = (unsigned long long*)((char*)d_ws + (2u << 20));

    prep<<<QUADS * N_INPUTS / 1024, 1024, 0, stream>>>(x, xq);
    dim3 grid(SLICES, QUADS);
    inhibit<<<grid, THREADS, 0, stream>>>(xq, det, x, pm);
    finalize<<<BATCH * (N_INPUTS / 32) / 256, 256, 0, stream>>>(pm, (float*)d_out);
}

// Round 8
// 88.026 us; speedup vs baseline: 3.0656x; 1.0930x over previous
//
#include <hip/hip_runtime.h>

#define N_INPUTS 16384
#define N_DET    65536
#define KD       32
#define BATCH    32
#define SLICES   32                        // det slices (2048 det each)
#define QUADS    8                         // 4 batch rows per block
#define DPB      (N_DET / SLICES)          // 2048 detectors per block
#define THREADS  1024                      // 16 waves, 1 block/CU (136 KB LDS)
                                           // -> 4 waves/SIMD, 128 VGPR cap

typedef unsigned short u16x4 __attribute__((ext_vector_type(4)));

// monotone saturating 16-bit key for f32: uniform 1/8192 resolution on
// [-4,4] (where all winners live for N(0,1) data). a<b => key(a)<=key(b),
// and key(a)<key(b) => a<b, so a UNIQUE key-max slot is the exact unique
// argmax. Equal keys (~2e-4 per det-batch, incl. saturation) go through the
// exact f32 resolve. ~100x fewer resolves than float-bit truncation.
__device__ __forceinline__ unsigned short key16(float f) {
    float t = fmaf(f, 8192.f, 32768.f);
    t = fminf(fmaxf(t, 0.f), 65535.f);
    return (unsigned short)(unsigned)__float2int_rn(t);
}

// compact bits {q, q+4, ..., q+28} of v into a byte
__device__ __forceinline__ unsigned c8(unsigned v, int q) {
    v = (v >> q) & 0x11111111u;
    v = (v | (v >> 3)) & 0x03030303u;
    v = (v | (v >> 6)) & 0x000F000Fu;
    v = (v | (v >> 12)) & 0xFFu;
    return v;
}

// ---------------------------------------------------------------------------
// prep: xq[quad][i] = packed key16 of x[4q..4q+3][i]. 4 coalesced streams.
// ---------------------------------------------------------------------------
__global__ __launch_bounds__(1024) void prep(const float* __restrict__ x,
                                             unsigned long long* __restrict__ xq) {
    const int gid  = blockIdx.x * 1024 + threadIdx.x;    // 0 .. 8*16384-1
    const int quad = gid >> 14, i = gid & (N_INPUTS - 1);
    const float* xb = x + (size_t)quad * 4 * N_INPUTS + i;
    unsigned long long k = 0;
#pragma unroll
    for (int q = 0; q < 4; ++q)
        k |= (unsigned long long)key16(xb[(size_t)q * N_INPUTS]) << (16 * q);
    xq[gid] = k;
}

// ---------------------------------------------------------------------------
// inhibit: one block = (4 batch rows as packed key16 quads) x (2048-det
// slice), 1024 threads (4 waves/SIMD -- R7's 2w/SIMD + serial loop was the
// regressor, not the quad structure). Per detector: 32 ds_read_b64 gathers
// serve FOUR batches (half of R0's DS work per batch-element). Packed-u16
// max tree; candidate mask per batch = slots attaining the key max (true
// argmax is always a candidate by monotonicity). Singleton (~99.98%) ->
// exact winner directly. Rare tie -> divergent exact f32 resolve from
// global x (L2-resident, strict > = first-max tie-break; handles duplicate
// ids and saturated keys exactly). Winner nibbles scattered as fire-and-
// forget ds_or. Live state ~100 VGPR: fits the 128 cap without spill
// (R4 lesson: verify via inhibit WRITE_SIZE ~KB, not MB).
// ---------------------------------------------------------------------------
__global__ __launch_bounds__(THREADS) void inhibit(
        const unsigned long long* __restrict__ xq,
        const int* __restrict__ det,
        const float* __restrict__ x,
        unsigned* __restrict__ pm) {
    __shared__ __align__(16) unsigned long long xs[N_INPUTS]; // 128 KB keys
    __shared__ unsigned fl[N_INPUTS / 8];                     // 8 KB nibbles

    const int slice = blockIdx.x;
    const int quad  = blockIdx.y;
    const int tid   = threadIdx.x;

    fl[tid] = 0u;                            // 2048 words / 1024 threads
    fl[tid + 1024] = 0u;

    // stage the quad's packed keys: coalesced 16B loads
    const ulonglong2* src = (const ulonglong2*)(xq + (size_t)quad * N_INPUTS);
    ulonglong2* dst = (ulonglong2*)xs;
#pragma unroll
    for (int k = 0; k < N_INPUTS / 2 / THREADS; ++k)
        dst[tid + k * THREADS] = src[tid + k * THREADS];
    __syncthreads();

    const int4* det4 = (const int4*)det;
    const u16x4* xsv = (const u16x4*)xs;

#pragma unroll 1
    for (int j = 0; j < DPB / THREADS; ++j) {      // 2 detectors per thread
        const int   d    = slice * DPB + j * THREADS + tid;
        const int4* drow = det4 + (size_t)d * 8;
        int ids[KD];
#pragma unroll
        for (int q = 0; q < 8; ++q) {
            int4 r = drow[q];
            ids[q * 4 + 0] = r.x; ids[q * 4 + 1] = r.y;
            ids[q * 4 + 2] = r.z; ids[q * 4 + 3] = r.w;
        }

        u16x4 k[KD];                               // 32-deep b64 burst, 4 rows
#pragma unroll
        for (int s = 0; s < KD; ++s) k[s] = xsv[ids[s]];

        // packed-u16 max tree (log depth, static indices)
        u16x4 t[16];
#pragma unroll
        for (int i = 0; i < 16; ++i) t[i] = __builtin_elementwise_max(k[2 * i], k[2 * i + 1]);
#pragma unroll
        for (int i = 0; i < 8; ++i)  t[i] = __builtin_elementwise_max(t[2 * i], t[2 * i + 1]);
#pragma unroll
        for (int i = 0; i < 4; ++i)  t[i] = __builtin_elementwise_max(t[2 * i], t[2 * i + 1]);
        t[0] = __builtin_elementwise_max(t[0], t[1]);
        t[2] = __builtin_elementwise_max(t[2], t[3]);
        const u16x4 km = __builtin_elementwise_max(t[0], t[2]);

        // candidate masks per batch (slots attaining the key-max)
        unsigned eq0 = 0, eq1 = 0, eq2 = 0, eq3 = 0;
#pragma unroll
        for (int s = 0; s < KD; ++s) {
            eq0 |= (unsigned)(k[s][0] == km[0]) << s;
            eq1 |= (unsigned)(k[s][1] == km[1]) << s;
            eq2 |= (unsigned)(k[s][2] == km[2]) << s;
            eq3 |= (unsigned)(k[s][3] == km[3]) << s;
        }

        // exact winner slot per batch; ~2e-4 divergent f32 resolve for ties
        int sw0, sw1, sw2, sw3;
#define RESOLVE(EQ, SW, Q)                                                     \
        SW = __builtin_ctz(EQ);                                                \
        if (__builtin_expect((int)(EQ & (EQ - 1)), 0)) {                       \
            const float* xb = x + (size_t)(quad * 4 + (Q)) * N_INPUTS;         \
            float best = xb[ids[SW]];                                          \
            unsigned m = EQ & (EQ - 1);                                        \
            do {                                                               \
                int s = __builtin_ctz(m); m &= m - 1;                          \
                float v = xb[ids[s]];                                          \
                if (v > best) { best = v; SW = s; }   /* strict > = first-max */\
            } while (m);                                                       \
        }
        RESOLVE(eq0, sw0, 0)
        RESOLVE(eq1, sw1, 1)
        RESOLVE(eq2, sw2, 2)
        RESOLVE(eq3, sw3, 3)
#undef RESOLVE

        const unsigned w0 = 1u << sw0, w1 = 1u << sw1;
        const unsigned w2 = 1u << sw2, w3 = 1u << sw3;
#pragma unroll
        for (int s = 0; s < KD; ++s) {
            unsigned nib = 0xFu ^ (((w0 >> s) & 1u) | (((w1 >> s) & 1u) << 1) |
                                  (((w2 >> s) & 1u) << 2) | (((w3 >> s) & 1u) << 3));
            int id = ids[s];
            atomicOr(&fl[id >> 3], nib << ((id & 7) * 4));   // ds_or, no rtn
        }
    }
    __syncthreads();

    // pack: thread (w, qh) emits pm word w for batches 2qh, 2qh+1
    const int w  = tid & 511;
    const int qh = tid >> 9;
    unsigned f0 = fl[4 * w + 0], f1 = fl[4 * w + 1];
    unsigned f2 = fl[4 * w + 2], f3 = fl[4 * w + 3];
#pragma unroll
    for (int qq = 0; qq < 2; ++qq) {
        int q = qh * 2 + qq;
        unsigned out32 = c8(f0, q) | (c8(f1, q) << 8) | (c8(f2, q) << 16) | (c8(f3, q) << 24);
        pm[((size_t)(slice * BATCH + quad * 4 + q)) * (N_INPUTS / 32) + w] = out32;
    }
}

// ---------------------------------------------------------------------------
// finalize: thread = (batch, 32-input group). OR the 32 slice words, emit
// 32 floats as 8 float4 stores. Total read traffic 2 MB.
// ---------------------------------------------------------------------------
__global__ __launch_bounds__(256) void finalize(const unsigned* __restrict__ pm,
                                                float* __restrict__ out) {
    const int t = blockIdx.x * 256 + threadIdx.x;   // 0 .. 32*512-1
    const int b = t >> 9, g = t & 511;
    unsigned acc = 0;
#pragma unroll
    for (int s = 0; s < SLICES; ++s)
        acc |= pm[((size_t)(s * BATCH + b)) * (N_INPUTS / 32) + g];
    float4* o = (float4*)(out + (size_t)b * N_INPUTS + g * 32);
#pragma unroll
    for (int v = 0; v < 8; ++v) {
        float4 r;
        r.x = ((acc >> (4 * v + 0)) & 1u) ? 0.0f : 1.0f;
        r.y = ((acc >> (4 * v + 1)) & 1u) ? 0.0f : 1.0f;
        r.z = ((acc >> (4 * v + 2)) & 1u) ? 0.0f : 1.0f;
        r.w = ((acc >> (4 * v + 3)) & 1u) ? 0.0f : 1.0f;
        o[v] = r;
    }
}

extern "C" void kernel_launch(void* const* d_in, const int* in_sizes, int n_in,
                              void* d_out, int out_size, void* d_ws, size_t ws_size,
                              hipStream_t stream) {
    const float* x   = (const float*)d_in[0];              // [B, N_INPUTS] f32
    const int*   det = (const int*)d_in[1];                // [N_DET, K] i32

    // ws layout: pm 2MB | xq 1MB
    unsigned* pm = (unsigned*)d_ws;
    unsigned long long* xq = (unsigned long long*)((char*)d_ws + (2u << 20));

    prep<<<QUADS * N_INPUTS / 1024, 1024, 0, stream>>>(x, xq);
    dim3 grid(SLICES, QUADS);
    inhibit<<<grid, THREADS, 0, stream>>>(xq, det, x, pm);
    finalize<<<BATCH * (N_INPUTS / 32) / 256, 256, 0, stream>>>(pm, (float*)d_out);
}